// Round 1
// 764.351 us; speedup vs baseline: 1.0185x; 1.0185x over previous
//
#include <hip/hip_runtime.h>
#include <hip/hip_bf16.h>

// Problem constants
#define BB   128
#define DV   2048
#define SS   196
#define DQ   2048
#define DA   1200
#define DAP  1280      // DA padded to 5*256 MFMA n-tiles
#define GG   4
#define DH   2048
#define NANS 3000
#define NANSP 3008     // 47*64
#define MROWS (BB*SS)  // 25088 = 196 * 128 exactly
#define NT   5         // n-tiles (256-wide) in big GEMM
#define KSPLIT 8
#define KCHUNK (DV/KSPLIT)  // 256
#define NQ   (DAP + DH)     // 3328 merged q-branch cols

typedef __attribute__((ext_vector_type(8))) short bf16x8;
typedef __attribute__((ext_vector_type(4))) float f32x4;

__device__ __forceinline__ float fast_tanh(float x) {
    float e = __expf(2.0f * x);
    return 1.0f - 2.0f * __builtin_amdgcn_rcpf(e + 1.0f);
}

__device__ __forceinline__ void async_copy16(const void* gsrc, void* ldst) {
    __builtin_amdgcn_global_load_lds(
        (const __attribute__((address_space(1))) void*)gsrc,
        (__attribute__((address_space(3))) void*)ldst, 16, 0, 0);
}

// pad bv (DA->DAP) and Wa ([DA][4] -> [DAP][4], pad rows 0)
__global__ void pad_misc(const float* __restrict__ bv, const float* __restrict__ Wa,
                         float* __restrict__ bvp, float* __restrict__ wap) {
    int i = blockIdx.x * 256 + threadIdx.x;
    if (i < DAP) bvp[i] = (i < DA) ? bv[i] : 0.f;
    if (i < DAP * GG) {
        int d = i >> 2;
        wap[i] = (d < DA) ? Wa[i] : 0.f;
    }
}

// ---------------------------------------------------------------------------
// K0a: v [B][DV][S] fp32 -> v_t [(b*S+s)][DV] bf16. 128c x 64s tiles; stores
// are full-wave 256B coalesced (64 lanes x bf16x2 over 128 channels).
// ---------------------------------------------------------------------------
__global__ __launch_bounds__(256) void transpose_v(const float* __restrict__ v,
                                                   __hip_bfloat16* __restrict__ vt) {
    __shared__ float tile[128][65];
    const int b  = blockIdx.z;
    const int c0 = blockIdx.x * 128;
    const int s0 = blockIdx.y * 64;
    const int t  = threadIdx.x;
    const int sl = t & 63;
    const int cr = t >> 6;
    const float* src = v + (size_t)b * DV * SS;
    const int sg = s0 + sl;
    const bool sok = sg < SS;
#pragma unroll
    for (int i = 0; i < 32; ++i) {
        int c = cr + i * 4;
        tile[c][sl] = sok ? src[(size_t)(c0 + c) * SS + sg] : 0.f;
    }
    __syncthreads();
    const int cp = (t & 63) * 2;
#pragma unroll
    for (int i = 0; i < 16; ++i) {
        int s = (t >> 6) + i * 4;
        int sgl = s0 + s;
        if (sgl < SS) {
            __hip_bfloat162 h2;
            h2.x = __float2bfloat16(tile[cp][s]);
            h2.y = __float2bfloat16(tile[cp + 1][s]);
            *(__hip_bfloat162*)(vt + ((size_t)b * SS + sgl) * DV + c0 + cp) = h2;
        }
    }
}

// ---------------------------------------------------------------------------
// K0b: Wv [DV][DA] fp32 -> wvt [DAP][DV] bf16 (B^T layout), pad rows zeroed
// ---------------------------------------------------------------------------
__global__ __launch_bounds__(256) void transpose_w(const float* __restrict__ Wv,
                                                   __hip_bfloat16* __restrict__ wvt) {
    __shared__ float tile[64][65];
    const int d0 = blockIdx.x * 64;
    const int c0 = blockIdx.y * 64;
    const int t  = threadIdx.x;
    const int col  = t & 63;
    const int rowb = t >> 6;
#pragma unroll
    for (int i = 0; i < 16; ++i) {
        int c = rowb + i * 4;
        int d = d0 + col;
        tile[c][col] = (d < DA) ? Wv[(size_t)(c0 + c) * DA + d] : 0.f;
    }
    __syncthreads();
#pragma unroll
    for (int i = 0; i < 16; ++i) {
        int dl = rowb + i * 4;
        wvt[(size_t)(d0 + dl) * DV + c0 + col] = __float2bfloat16(tile[col][dl]);
    }
}

// ---------------------------------------------------------------------------
// Split-K fp32 partial GEMM: Cp[ks][128][Npad] = A[128,kchunk] * B[kchunk,64tile]
// grid (ntiles, KSPLIT). SEL 0: classifier | SEL 1: glimpse fusion | SEL 2:
// merged q-branch (cols [0,DAP) -> Wq_att, cols [DAP,NQ) -> Wqf).
// ---------------------------------------------------------------------------
template <int SEL>
__global__ __launch_bounds__(256) void gemm_partial(
    const float* __restrict__ A, int lda,
    const float* __restrict__ Bm, const float* __restrict__ B2,
    float* __restrict__ Cp, int Npad) {
    __shared__ float As[64 * 132];   // As[kk][m]
    __shared__ float Bs[64 * 68];    // Bs[kk][n]
    const int t     = threadIdx.x;
    const int n0    = blockIdx.x * 64;
    const int kbase = blockIdx.y * KCHUNK;

    const float* Aeff = A;
    const float* Beff;
    int ldb, ncol0, nlim;
    if (SEL == 0) {            // classifier: B=Wc [2048][3000]
        Beff = Bm; ldb = NANS; ncol0 = n0; nlim = NANS;
    } else if (SEL == 1) {     // fusion: A=vatt per glimpse, B=Wf[g] [2048][512]
        int gg = n0 >> 9;
        Aeff = A + gg * 2048;
        Beff = Bm + (size_t)gg * 2048 * 512;
        ldb = 512; ncol0 = n0 & 511; nlim = 1 << 30;
    } else {                   // merged q-branch
        if (n0 < DAP) { Beff = Bm; ldb = DA; ncol0 = n0;      nlim = DA; }
        else          { Beff = B2; ldb = DH; ncol0 = n0 - DAP; nlim = 1 << 30; }
    }

    const int tm = (t & 31) * 4;
    const int tn = (t >> 5) * 8;
    float acc[4][8] = {};

    for (int k0 = kbase; k0 < kbase + KCHUNK; k0 += 64) {
        {
            int kk = t & 63, mb = (t >> 6) * 32;
#pragma unroll
            for (int i = 0; i < 32; ++i)
                As[kk * 132 + mb + i] = Aeff[(size_t)(mb + i) * lda + k0 + kk];
        }
        {
            int j = t & 63, kr = t >> 6;
            bool ok = (ncol0 + j) < nlim;
#pragma unroll
            for (int i = 0; i < 16; ++i) {
                int k = kr + i * 4;
                Bs[k * 68 + j] = ok ? Beff[(size_t)(k0 + k) * ldb + ncol0 + j] : 0.f;
            }
        }
        __syncthreads();
#pragma unroll
        for (int kk = 0; kk < 64; ++kk) {
            const float4 av = *(const float4*)(As + kk * 132 + tm);
            const float4 b0 = *(const float4*)(Bs + kk * 68 + tn);
            const float4 b1 = *(const float4*)(Bs + kk * 68 + tn + 4);
            const float am[4] = {av.x, av.y, av.z, av.w};
#pragma unroll
            for (int i = 0; i < 4; ++i) {
                acc[i][0] += am[i] * b0.x; acc[i][1] += am[i] * b0.y;
                acc[i][2] += am[i] * b0.z; acc[i][3] += am[i] * b0.w;
                acc[i][4] += am[i] * b1.x; acc[i][5] += am[i] * b1.y;
                acc[i][6] += am[i] * b1.z; acc[i][7] += am[i] * b1.w;
            }
        }
        __syncthreads();
    }
#pragma unroll
    for (int i = 0; i < 4; ++i) {
        size_t base = ((size_t)blockIdx.y * 128 + tm + i) * Npad + n0 + tn;
        float4 v0 = {acc[i][0], acc[i][1], acc[i][2], acc[i][3]};
        float4 v1 = {acc[i][4], acc[i][5], acc[i][6], acc[i][7]};
        *(float4*)(Cp + base) = v0;
        *(float4*)(Cp + base + 4) = v1;
    }
}

// Generic epilogue: MODE 0: +bias (classifier) | MODE 2: MLB glimpse fusion
template <int MODE>
__global__ __launch_bounds__(256) void gemm_epilogue(
    const float* __restrict__ Cp, int Npad, int Nreal,
    const float* __restrict__ bias, const float* __restrict__ aux,
    float* __restrict__ out, int ldo) {
    int n = blockIdx.x * 256 + threadIdx.x;
    int m = blockIdx.y;
    if (n >= Npad) return;
    float s = 0.f;
#pragma unroll
    for (int ks = 0; ks < KSPLIT; ++ks)
        s += Cp[((size_t)ks * 128 + m) * Npad + n];
    if (MODE == 0) {
        if (n >= Nreal) return;
        out[(size_t)m * ldo + n] = s + bias[n];
    } else {
        float xv = fast_tanh(s + bias[n]);
        out[(size_t)m * ldo + n] = fast_tanh(xv * aux[(size_t)m * 2048 + n]);
    }
}

// q-branch epilogue: cols [0,DAP) -> qatt (tanh, pad->0), [DAP,NQ) -> qfus
__global__ __launch_bounds__(256) void epilogue_q(
    const float* __restrict__ Cp,
    const float* __restrict__ bqa, const float* __restrict__ bqf,
    float* __restrict__ qatt, float* __restrict__ qfus) {
    int n = blockIdx.x * 256 + threadIdx.x;
    int m = blockIdx.y;
    if (n >= NQ) return;
    float s = 0.f;
#pragma unroll
    for (int ks = 0; ks < KSPLIT; ++ks)
        s += Cp[((size_t)ks * 128 + m) * NQ + n];
    if (n < DAP) {
        qatt[(size_t)m * DAP + n] = (n < DA) ? fast_tanh(s + bqa[n]) : 0.f;
    } else {
        int j = n - DAP;
        qfus[(size_t)m * DH + j] = fast_tanh(s + bqf[j]);
    }
}

// ---------------------------------------------------------------------------
// K1: big MFMA GEMM, 256x256 tile, BK=64, 8 waves (2M x 4N), double-buffered
// LDS with counted vmcnt(8) (T3+T4: loads for tile k+1 stay in flight across
// the barrier; never drain to 0 in the loop), s_setprio around MFMA clusters
// (T5). XOR chunk-swizzle staging (pre-swizzled global source, linear
// global_load_lds dest, swizzled ds_read_b128) -> conflict-free reads.
// Fused epilogue: xv=tanh(.), xa=tanh(xv*q), per-wc score partials stored
// (plain, no atomics) into LDS aliased over the dead staging buffers, then
// combined -> scores_p[nt][row][4].
// Grid 490 = 98 m-tiles x 5 n-tiles, grouped 8x5 so each XCD reuses one
// A-tile from its own L2 across all 5 n-tiles.
// ---------------------------------------------------------------------------
__global__ __launch_bounds__(512, 2) void big_gemm(
    const __hip_bfloat16* __restrict__ vt,
    const __hip_bfloat16* __restrict__ wt,
    const float* __restrict__ bvp,
    const float* __restrict__ qatt,
    const float* __restrict__ wap,
    float* __restrict__ scores_p) {
    // staging: buf{0,1} x (As 32KB | Bs 32KB) = 128KB. Reused by epilogue as
    // sc[4 wc][256 rows][4 g] partial-score buffer (16KB).
    __shared__ __align__(16) char lds[131072];
    __shared__ __align__(16) float wa_s[256 * 4];
    __shared__ float qs[3 * 256];

    const int t    = threadIdx.x;
    const int lane = t & 63;
    const int w    = t >> 6;        // wave 0..7
    const int wr   = w >> 2;        // m-half 0..1
    const int wc   = w & 3;         // n-quarter 0..3

    // grid de-swizzle: 12 groups of (8 mt x 5 nt) + tail (2 mt x 5 nt)
    int bid = blockIdx.x;
    int grp = bid / 40, r = bid % 40;
    int mt, nt;
    if (grp < 12) { mt = grp * 8 + (r & 7); nt = r >> 3; }
    else          { mt = 96 + (r & 1);      nt = r >> 1; }
    const int m0 = mt * 256, n0 = nt * 256;
    const int b_lo = m0 / SS;              // 256-row tile spans <= 3 batches
    const int bs1  = (b_lo + 1) * SS;
    const int bs2  = (b_lo + 2) * SS;

    // small prologue loads (wa tile, q rows for up to 3 batches)
    if (t < 256) *(float4*)(wa_s + t * 4) = *(const float4*)(wap + (n0 + t) * 4);
    {
        int j = t >> 8, c = t & 255;       // j=0,1 over 512 threads
        int b = b_lo + j;
        qs[t] = (b < BB) ? qatt[(size_t)b * DAP + n0 + c] : 0.f;
        if (t < 256) {
            int b2 = b_lo + 2;
            qs[512 + t] = (b2 < BB) ? qatt[(size_t)b2 * DAP + n0 + t] : 0.f;
        }
    }

    // Staging: per wave, per issue j: rows j*64 + w*8 + (lane>>3), chunk lane&7.
    // Global source chunk pre-swizzled by ^(row&7) so the linear LDS dest ends
    // up with stored chunk p of row R holding global chunk p ^ (R&7).
    const int srow   = lane >> 3;
    const int schunk = (lane & 7) ^ srow;
    const __hip_bfloat16* aG = vt + (size_t)(m0 + w * 8 + srow) * DV + schunk * 8;
    const __hip_bfloat16* bG = wt + (size_t)(n0 + w * 8 + srow) * DV + schunk * 8;

    auto STAGE = [&](int buf, int kk) {
        char* aL = lds + buf * 65536 + w * 1024;
        char* bL = aL + 32768;
#pragma unroll
        for (int j = 0; j < 4; ++j) {
            async_copy16(aG + (size_t)(j * 64) * DV + kk, aL + j * 8192);
            async_copy16(bG + (size_t)(j * 64) * DV + kk, bL + j * 8192);
        }
    };

    f32x4 acc[8][4];
#pragma unroll
    for (int i = 0; i < 8; ++i)
#pragma unroll
        for (int j = 0; j < 4; ++j) acc[i][j] = (f32x4){0.f, 0.f, 0.f, 0.f};

    STAGE(0, 0);                       // tile 0 -> buf0 (8 issues in flight)

    for (int kt = 0; kt < 32; ++kt) {
        const int cur = kt & 1;
        __builtin_amdgcn_s_barrier();  // all waves done reading buf[cur^1]
        if (kt < 31) {
            STAGE(cur ^ 1, (kt + 1) * 64);                 // +8 in flight
            asm volatile("s_waitcnt vmcnt(8)" ::: "memory"); // tile kt landed
        } else {
            asm volatile("s_waitcnt vmcnt(0)" ::: "memory");
        }
        __builtin_amdgcn_s_barrier();  // everyone's tile-kt stores visible

        const __hip_bfloat16* As = (const __hip_bfloat16*)(lds + cur * 65536);
        const __hip_bfloat16* Bs = As + 16384;  // +32KB
        bf16x8 a[4], b[4];
#pragma unroll
        for (int ks = 0; ks < 2; ++ks) {
            const int cx = ((ks * 4 + (lane >> 4)) ^ (lane & 7)) * 8;
#pragma unroll
            for (int ni = 0; ni < 4; ++ni)
                b[ni] = *(const bf16x8*)(Bs + (wc * 64 + ni * 16 + (lane & 15)) * 64 + cx);
#pragma unroll
            for (int h = 0; h < 2; ++h) {
#pragma unroll
                for (int q = 0; q < 4; ++q)
                    a[q] = *(const bf16x8*)(As + (wr * 128 + (h * 4 + q) * 16 + (lane & 15)) * 64 + cx);
                __builtin_amdgcn_s_setprio(1);
#pragma unroll
                for (int q = 0; q < 4; ++q)
#pragma unroll
                    for (int ni = 0; ni < 4; ++ni)
                        acc[h * 4 + q][ni] = __builtin_amdgcn_mfma_f32_16x16x32_bf16(
                            a[q], b[ni], acc[h * 4 + q][ni], 0, 0, 0);
                __builtin_amdgcn_s_setprio(0);
            }
        }
    }

    // ---- fused epilogue ----
    __syncthreads();                   // drain; staging LDS is now dead
    float* sc = (float*)lds;           // [4][256][4] per-wc partials

    // C/D layout: col = lane&15 (+16*ni), row = (lane>>4)*4 + rr (+16*mi)
    const int colb_l = wc * 64 + (lane & 15);
    const int colb_g = n0 + colb_l;
    float bvv[4];
    float4 wv[4];
#pragma unroll
    for (int ni = 0; ni < 4; ++ni) {
        bvv[ni] = bvp[colb_g + ni * 16];
        wv[ni]  = *(const float4*)(wa_s + (colb_l + ni * 16) * 4);
    }
#pragma unroll
    for (int mi = 0; mi < 8; ++mi) {
#pragma unroll
        for (int rr = 0; rr < 4; ++rr) {
            int lrow = wr * 128 + mi * 16 + ((lane >> 4) << 2) + rr;  // 0..255
            int row  = m0 + lrow;
            int qoff = (row >= bs1 ? 256 : 0) + (row >= bs2 ? 256 : 0);
            float p0 = 0.f, p1 = 0.f, p2 = 0.f, p3 = 0.f;
#pragma unroll
            for (int ni = 0; ni < 4; ++ni) {
                float xv = fast_tanh(acc[mi][ni][rr] + bvv[ni]);
                float xa = fast_tanh(xv * qs[qoff + colb_l + ni * 16]);
                p0 += xa * wv[ni].x; p1 += xa * wv[ni].y;
                p2 += xa * wv[ni].z; p3 += xa * wv[ni].w;
            }
#pragma unroll
            for (int mk = 1; mk < 16; mk <<= 1) {
                p0 += __shfl_xor(p0, mk); p1 += __shfl_xor(p1, mk);
                p2 += __shfl_xor(p2, mk); p3 += __shfl_xor(p3, mk);
            }
            // each (wc, lrow) written exactly once (wr splits lrow ranges)
            if ((lane & 15) == 0)
                *(float4*)(sc + ((size_t)wc * 256 + lrow) * 4) =
                    (float4){p0, p1, p2, p3};
        }
    }
    __syncthreads();
    if (t < 256) {
        float4 s0 = *(float4*)(sc + (0 * 256 + t) * 4);
        float4 s1 = *(float4*)(sc + (1 * 256 + t) * 4);
        float4 s2 = *(float4*)(sc + (2 * 256 + t) * 4);
        float4 s3 = *(float4*)(sc + (3 * 256 + t) * 4);
        float4 s = {s0.x + s1.x + s2.x + s3.x, s0.y + s1.y + s2.y + s3.y,
                    s0.z + s1.z + s2.z + s3.z, s0.w + s1.w + s2.w + s3.w};
        *(float4*)(scores_p + ((size_t)nt * MROWS + m0 + t) * 4) = s;
    }
}

// ---------------------------------------------------------------------------
// K2: sum score partials -> softmax over s -> glimpse pooling (512-ch chunk).
// ---------------------------------------------------------------------------
__global__ __launch_bounds__(256) void softmax_pool(
    const float* __restrict__ scores_p,
    const __hip_bfloat16* __restrict__ vt,
    float* __restrict__ vatt) {
    __shared__ __align__(16) float att[SS * GG];
    const int b = blockIdx.y;
    const int t = threadIdx.x;
    if (t < SS) {
        float4 s = {0.f, 0.f, 0.f, 0.f};
#pragma unroll
        for (int ntile = 0; ntile < NT; ++ntile) {
            float4 p = *(const float4*)(scores_p + ((size_t)ntile * MROWS + b * SS + t) * 4);
            s.x += p.x; s.y += p.y; s.z += p.z; s.w += p.w;
        }
        *(float4*)(att + t * 4) = s;
    }
    __syncthreads();
    {
        const int g = t >> 6;
        const int lane = t & 63;
        float mx = -3.0e38f;
        for (int s = lane; s < SS; s += 64) mx = fmaxf(mx, att[s * 4 + g]);
#pragma unroll
        for (int m = 32; m > 0; m >>= 1) mx = fmaxf(mx, __shfl_xor(mx, m));
        float sum = 0.f;
        for (int s = lane; s < SS; s += 64) sum += __expf(att[s * 4 + g] - mx);
#pragma unroll
        for (int m = 32; m > 0; m >>= 1) sum += __shfl_xor(sum, m);
        float inv = __builtin_amdgcn_rcpf(sum);
        for (int s = lane; s < SS; s += 64) att[s * 4 + g] = __expf(att[s * 4 + g] - mx) * inv;
    }
    __syncthreads();
    const int c = blockIdx.x * 512 + t * 2;
    const __hip_bfloat16* vp = vt + (size_t)b * SS * DV + c;
    float a00 = 0, a01 = 0, a02 = 0, a03 = 0;
    float a10 = 0, a11 = 0, a12 = 0, a13 = 0;
#pragma unroll 4
    for (int s = 0; s < SS; ++s) {
        unsigned u = *(const unsigned*)(vp + (size_t)s * DV);
        float v0 = __uint_as_float(u << 16);
        float v1 = __uint_as_float(u & 0xffff0000u);
        float4 aw = *(const float4*)(att + s * 4);
        a00 += v0 * aw.x; a01 += v0 * aw.y; a02 += v0 * aw.z; a03 += v0 * aw.w;
        a10 += v1 * aw.x; a11 += v1 * aw.y; a12 += v1 * aw.z; a13 += v1 * aw.w;
    }
    float* vb = vatt + (size_t)b * GG * DV;
    vb[0 * DV + c] = a00; vb[0 * DV + c + 1] = a10;
    vb[1 * DV + c] = a01; vb[1 * DV + c + 1] = a11;
    vb[2 * DV + c] = a02; vb[2 * DV + c + 1] = a12;
    vb[3 * DV + c] = a03; vb[3 * DV + c + 1] = a13;
}

// ---------------------------------------------------------------------------
extern "C" void kernel_launch(void* const* d_in, const int* in_sizes, int n_in,
                              void* d_out, int out_size, void* d_ws, size_t ws_size,
                              hipStream_t stream) {
    const float* input_v = (const float*)d_in[0];
    const float* x_q     = (const float*)d_in[1];
    const float* Wv      = (const float*)d_in[2];
    const float* bv      = (const float*)d_in[3];
    const float* Wq_att  = (const float*)d_in[4];
    const float* bq_att  = (const float*)d_in[5];
    const float* Wa      = (const float*)d_in[6];
    // d_in[7] = ba: constant over softmax axis -> cancels, unused.
    const float* Wf      = (const float*)d_in[8];
    const float* bf_     = (const float*)d_in[9];
    const float* Wqf     = (const float*)d_in[10];
    const float* bqf     = (const float*)d_in[11];
    const float* Wc      = (const float*)d_in[12];
    const float* bc      = (const float*)d_in[13];
    float* out = (float*)d_out;

    char* wsb = (char*)d_ws;
    size_t off = 0;
    auto carve = [&](size_t bytes) -> void* {
        void* p = wsb + off;
        off += (bytes + 255) & ~(size_t)255;
        return p;
    };
    __hip_bfloat16* vt  = (__hip_bfloat16*)carve((size_t)MROWS * DV * 2);   // 102.8 MB
    __hip_bfloat16* wvt = (__hip_bfloat16*)carve((size_t)DAP * DV * 2);     //   5.2 MB
    float* Cp       = (float*)carve((size_t)KSPLIT * 128 * NQ * 4);         //  13.6 MB
    float* scores_p = (float*)carve((size_t)NT * MROWS * GG * 4);           //   2.0 MB
    float* qatt = (float*)carve((size_t)BB * DAP * 4);
    float* qfus = (float*)carve((size_t)BB * DH * 4);
    float* bvp  = (float*)carve((size_t)DAP * 4);
    float* wap  = (float*)carve((size_t)DAP * GG * 4);
    float* vatt = (float*)carve((size_t)BB * GG * DV * 4);
    float* xbuf = (float*)carve((size_t)BB * DH * 4);
    (void)ws_size; (void)n_in; (void)in_sizes; (void)out_size;

    pad_misc<<<dim3(20), 256, 0, stream>>>(bv, Wa, bvp, wap);
    transpose_v<<<dim3(DV / 128, 4, BB), 256, 0, stream>>>(input_v, vt);
    transpose_w<<<dim3(DAP / 64, DV / 64), 256, 0, stream>>>(Wv, wvt);

    // merged q-branch GEMM (split-K fp32): cols [0,1280)=Wq_att, [1280,3328)=Wqf
    gemm_partial<2><<<dim3(NQ / 64, KSPLIT), 256, 0, stream>>>(
        x_q, DQ, Wq_att, Wqf, Cp, NQ);
    epilogue_q<<<dim3(NQ / 256, BB), 256, 0, stream>>>(Cp, bq_att, bqf, qatt, qfus);

    // big MFMA GEMM with fused score reduction -> scores_p (per-ntile partials)
    // grid: 12 groups of (8 mt x 5 nt) + tail 10 = 490 blocks of 512 threads
    big_gemm<<<dim3(490), 512, 0, stream>>>(vt, wvt, bvp, qatt, wap, scores_p);

    // softmax over spatial + glimpse pooling -> vatt [128][4][2048]
    softmax_pool<<<dim3(4, BB), 256, 0, stream>>>(scores_p, vt, vatt);

    // glimpse fusion: xbuf = tanh(tanh(vatt@Wf + bf) * qfus)
    gemm_partial<1><<<dim3(DH / 64, KSPLIT), 256, 0, stream>>>(
        vatt, GG * DV, Wf, nullptr, Cp, DH);
    gemm_epilogue<2><<<dim3(DH / 256, BB), 256, 0, stream>>>(
        Cp, DH, DH, bf_, qfus, xbuf, DH);

    // classifier: out = xbuf @ Wc + bc
    gemm_partial<0><<<dim3(NANSP / 64, KSPLIT), 256, 0, stream>>>(
        xbuf, DH, Wc, nullptr, Cp, NANSP);
    gemm_epilogue<0><<<dim3(NANSP / 256 + 1, BB), 256, 0, stream>>>(
        Cp, NANSP, NANS, bc, nullptr, out, NANS);
}

// Round 2
// 677.695 us; speedup vs baseline: 1.1487x; 1.1279x over previous
//
#include <hip/hip_runtime.h>
#include <hip/hip_bf16.h>

// Problem constants
#define BB   128
#define DV   2048
#define SS   196
#define DQ   2048
#define DA   1200
#define DAP  1280      // DA padded to 5*256 MFMA n-tiles
#define GG   4
#define DH   2048
#define NANS 3000
#define NANSP 3008     // 47*64
#define MROWS (BB*SS)  // 25088 = 196 * 128 exactly
#define NT   5         // n-tiles (256-wide) in big GEMM
#define KSPLIT 8
#define KCHUNK (DV/KSPLIT)  // 256
#define NQ   (DAP + DH)     // 3328 merged q-branch cols

typedef __attribute__((ext_vector_type(8))) short bf16x8;
typedef __attribute__((ext_vector_type(4))) float f32x4;

__device__ __forceinline__ float fast_tanh(float x) {
    float e = __expf(2.0f * x);
    return 1.0f - 2.0f * __builtin_amdgcn_rcpf(e + 1.0f);
}

__device__ __forceinline__ void async_copy16(const void* gsrc, void* ldst) {
    __builtin_amdgcn_global_load_lds(
        (const __attribute__((address_space(1))) void*)gsrc,
        (__attribute__((address_space(3))) void*)ldst, 16, 0, 0);
}

// pad bv (DA->DAP) and Wa ([DA][4] -> [DAP][4], pad rows 0)
__global__ void pad_misc(const float* __restrict__ bv, const float* __restrict__ Wa,
                         float* __restrict__ bvp, float* __restrict__ wap) {
    int i = blockIdx.x * 256 + threadIdx.x;
    if (i < DAP) bvp[i] = (i < DA) ? bv[i] : 0.f;
    if (i < DAP * GG) {
        int d = i >> 2;
        wap[i] = (d < DA) ? Wa[i] : 0.f;
    }
}

// ---------------------------------------------------------------------------
// K0a: v [B][DV][S] fp32 -> v_t [(b*S+s)][DV] bf16.
// No LDS: lane = s (coalesced 256B reads per row), each thread produces 16
// consecutive channels of one output row (2x bf16x8 stores; 64B-aligned runs
// per row merged in L2). 16 independent loads in flight per thread.
// ---------------------------------------------------------------------------
__global__ __launch_bounds__(256) void transpose_v(const float* __restrict__ v,
                                                   __hip_bfloat16* __restrict__ vt) {
    const int b  = blockIdx.z;
    const int c0 = blockIdx.x * 64 + (threadIdx.x >> 6) * 16;  // 16 c per thread
    const int s  = blockIdx.y * 64 + (threadIdx.x & 63);
    if (s >= SS) return;
    const float* src = v + (size_t)b * DV * SS + (size_t)c0 * SS + s;
    float f[16];
#pragma unroll
    for (int i = 0; i < 16; ++i) f[i] = src[(size_t)i * SS];
    union { bf16x8 v8; __hip_bfloat16 h[8]; } u0, u1;
#pragma unroll
    for (int i = 0; i < 8; ++i) {
        u0.h[i] = __float2bfloat16(f[i]);
        u1.h[i] = __float2bfloat16(f[8 + i]);
    }
    __hip_bfloat16* dst = vt + ((size_t)b * SS + s) * DV + c0;
    *(bf16x8*)dst = u0.v8;
    *(bf16x8*)(dst + 8) = u1.v8;
}

// ---------------------------------------------------------------------------
// K0b: Wv [DV][DA] fp32 -> wvt [DAP][DV] bf16 (B^T layout), pad rows zeroed
// ---------------------------------------------------------------------------
__global__ __launch_bounds__(256) void transpose_w(const float* __restrict__ Wv,
                                                   __hip_bfloat16* __restrict__ wvt) {
    __shared__ float tile[64][65];
    const int d0 = blockIdx.x * 64;
    const int c0 = blockIdx.y * 64;
    const int t  = threadIdx.x;
    const int col  = t & 63;
    const int rowb = t >> 6;
#pragma unroll
    for (int i = 0; i < 16; ++i) {
        int c = rowb + i * 4;
        int d = d0 + col;
        tile[c][col] = (d < DA) ? Wv[(size_t)(c0 + c) * DA + d] : 0.f;
    }
    __syncthreads();
#pragma unroll
    for (int i = 0; i < 16; ++i) {
        int dl = rowb + i * 4;
        wvt[(size_t)(d0 + dl) * DV + c0 + col] = __float2bfloat16(tile[col][dl]);
    }
}

// ---------------------------------------------------------------------------
// Split-K fp32 partial GEMM: Cp[ks][128][Npad] = A[128,kchunk] * B[kchunk,64tile]
// grid (ntiles, KSPLIT). SEL 0: classifier | SEL 1: glimpse fusion | SEL 2:
// merged q-branch (cols [0,DAP) -> Wq_att, cols [DAP,NQ) -> Wqf).
// ---------------------------------------------------------------------------
template <int SEL>
__global__ __launch_bounds__(256) void gemm_partial(
    const float* __restrict__ A, int lda,
    const float* __restrict__ Bm, const float* __restrict__ B2,
    float* __restrict__ Cp, int Npad) {
    __shared__ float As[64 * 132];   // As[kk][m]
    __shared__ float Bs[64 * 68];    // Bs[kk][n]
    const int t     = threadIdx.x;
    const int n0    = blockIdx.x * 64;
    const int kbase = blockIdx.y * KCHUNK;

    const float* Aeff = A;
    const float* Beff;
    int ldb, ncol0, nlim;
    if (SEL == 0) {            // classifier: B=Wc [2048][3000]
        Beff = Bm; ldb = NANS; ncol0 = n0; nlim = NANS;
    } else if (SEL == 1) {     // fusion: A=vatt per glimpse, B=Wf[g] [2048][512]
        int gg = n0 >> 9;
        Aeff = A + gg * 2048;
        Beff = Bm + (size_t)gg * 2048 * 512;
        ldb = 512; ncol0 = n0 & 511; nlim = 1 << 30;
    } else {                   // merged q-branch
        if (n0 < DAP) { Beff = Bm; ldb = DA; ncol0 = n0;      nlim = DA; }
        else          { Beff = B2; ldb = DH; ncol0 = n0 - DAP; nlim = 1 << 30; }
    }

    const int tm = (t & 31) * 4;
    const int tn = (t >> 5) * 8;
    float acc[4][8] = {};

    for (int k0 = kbase; k0 < kbase + KCHUNK; k0 += 64) {
        {
            int kk = t & 63, mb = (t >> 6) * 32;
#pragma unroll
            for (int i = 0; i < 32; ++i)
                As[kk * 132 + mb + i] = Aeff[(size_t)(mb + i) * lda + k0 + kk];
        }
        {
            int j = t & 63, kr = t >> 6;
            bool ok = (ncol0 + j) < nlim;
#pragma unroll
            for (int i = 0; i < 16; ++i) {
                int k = kr + i * 4;
                Bs[k * 68 + j] = ok ? Beff[(size_t)(k0 + k) * ldb + ncol0 + j] : 0.f;
            }
        }
        __syncthreads();
#pragma unroll
        for (int kk = 0; kk < 64; ++kk) {
            const float4 av = *(const float4*)(As + kk * 132 + tm);
            const float4 b0 = *(const float4*)(Bs + kk * 68 + tn);
            const float4 b1 = *(const float4*)(Bs + kk * 68 + tn + 4);
            const float am[4] = {av.x, av.y, av.z, av.w};
#pragma unroll
            for (int i = 0; i < 4; ++i) {
                acc[i][0] += am[i] * b0.x; acc[i][1] += am[i] * b0.y;
                acc[i][2] += am[i] * b0.z; acc[i][3] += am[i] * b0.w;
                acc[i][4] += am[i] * b1.x; acc[i][5] += am[i] * b1.y;
                acc[i][6] += am[i] * b1.z; acc[i][7] += am[i] * b1.w;
            }
        }
        __syncthreads();
    }
#pragma unroll
    for (int i = 0; i < 4; ++i) {
        size_t base = ((size_t)blockIdx.y * 128 + tm + i) * Npad + n0 + tn;
        float4 v0 = {acc[i][0], acc[i][1], acc[i][2], acc[i][3]};
        float4 v1 = {acc[i][4], acc[i][5], acc[i][6], acc[i][7]};
        *(float4*)(Cp + base) = v0;
        *(float4*)(Cp + base + 4) = v1;
    }
}

// Generic epilogue: MODE 0: +bias (classifier) | MODE 2: MLB glimpse fusion
template <int MODE>
__global__ __launch_bounds__(256) void gemm_epilogue(
    const float* __restrict__ Cp, int Npad, int Nreal,
    const float* __restrict__ bias, const float* __restrict__ aux,
    float* __restrict__ out, int ldo) {
    int n = blockIdx.x * 256 + threadIdx.x;
    int m = blockIdx.y;
    if (n >= Npad) return;
    float s = 0.f;
#pragma unroll
    for (int ks = 0; ks < KSPLIT; ++ks)
        s += Cp[((size_t)ks * 128 + m) * Npad + n];
    if (MODE == 0) {
        if (n >= Nreal) return;
        out[(size_t)m * ldo + n] = s + bias[n];
    } else {
        float xv = fast_tanh(s + bias[n]);
        out[(size_t)m * ldo + n] = fast_tanh(xv * aux[(size_t)m * 2048 + n]);
    }
}

// q-branch epilogue: cols [0,DAP) -> qatt (tanh, pad->0), [DAP,NQ) -> qfus
__global__ __launch_bounds__(256) void epilogue_q(
    const float* __restrict__ Cp,
    const float* __restrict__ bqa, const float* __restrict__ bqf,
    float* __restrict__ qatt, float* __restrict__ qfus) {
    int n = blockIdx.x * 256 + threadIdx.x;
    int m = blockIdx.y;
    if (n >= NQ) return;
    float s = 0.f;
#pragma unroll
    for (int ks = 0; ks < KSPLIT; ++ks)
        s += Cp[((size_t)ks * 128 + m) * NQ + n];
    if (n < DAP) {
        qatt[(size_t)m * DAP + n] = (n < DA) ? fast_tanh(s + bqa[n]) : 0.f;
    } else {
        int j = n - DAP;
        qfus[(size_t)m * DH + j] = fast_tanh(s + bqf[j]);
    }
}

// ---------------------------------------------------------------------------
// K1: big MFMA GEMM, 256x256 tile, BK=64, 8 waves (2M x 4N), 4-phase
// schedule per K-tile (T3+T4): LDS regions [buf][ks][A|B][256][32K bf16];
// phase (ks,mh) = {ds_read frags, stage 1 region-half (2 gload_lds) of the
// NEXT tile, counted vmcnt(4) at p1/p3 (never drains; 4 issues stay in
// flight across barriers), barrier, 16 MFMA under setprio, barrier}.
// Swizzle within 64B rows: stored chunk = g ^ ((row>>1)&3) -> 2-way (free)
// b128 reads; gload_lds dest is wave-linear (t*16), source pre-swizzled.
// Ledger (issues, 2 per STAGE_ITEM): prologue tile0(8) + vmcnt(4) -> ks0
// landed, ks1 in flight. kt.p1 vmcnt(4) -> kt.ks1 landed (read p2/p3);
// kt.p3 vmcnt(4) -> (kt+1).ks0 landed (read at kt+1.p0). kt==31: vmcnt(0)
// at p1 (drain, last tile). Region overwrite is >=2 barrier-phases after
// last reader (buf[cur^1].ks0 dead since (kt-1).p1, staged at kt.p0).
// Fused epilogue unchanged: per-wc score partials -> scores_p.
// ---------------------------------------------------------------------------
__global__ __launch_bounds__(512, 2) void big_gemm(
    const __hip_bfloat16* __restrict__ vt,
    const __hip_bfloat16* __restrict__ wt,
    const float* __restrict__ bvp,
    const float* __restrict__ qatt,
    const float* __restrict__ wap,
    float* __restrict__ scores_p) {
    // lds: buf*65536 + ks*32768 + mat*16384 + row*64 + chunk*16  (bytes)
    __shared__ __align__(16) char lds[131072];
    __shared__ __align__(16) float wa_s[256 * 4];
    __shared__ float qs[3 * 256];

    const int t    = threadIdx.x;
    const int lane = t & 63;
    const int w    = t >> 6;        // wave 0..7
    const int wr   = w >> 2;        // m-half 0..1
    const int wc   = w & 3;         // n-quarter 0..3

    // grid de-swizzle: 12 groups of (8 mt x 5 nt) + tail (2 mt x 5 nt)
    int bid = blockIdx.x;
    int grp = bid / 40, r = bid % 40;
    int mt, nt;
    if (grp < 12) { mt = grp * 8 + (r & 7); nt = r >> 3; }
    else          { mt = 96 + (r & 1);      nt = r >> 1; }
    const int m0 = mt * 256, n0 = nt * 256;
    const int b_lo = m0 / SS;              // 256-row tile spans <= 3 batches
    const int bs1  = (b_lo + 1) * SS;
    const int bs2  = (b_lo + 2) * SS;

    // small prologue loads (wa tile, q rows for up to 3 batches)
    if (t < 256) *(float4*)(wa_s + t * 4) = *(const float4*)(wap + (n0 + t) * 4);
    {
        int j = t >> 8, c = t & 255;       // j=0,1 over 512 threads
        int b = b_lo + j;
        qs[t] = (b < BB) ? qatt[(size_t)b * DAP + n0 + c] : 0.f;
        if (t < 256) {
            int b2 = b_lo + 2;
            qs[512 + t] = (b2 < BB) ? qatt[(size_t)b2 * DAP + n0 + t] : 0.f;
        }
    }
    __syncthreads();   // drain prologue vmem so the counted vmcnt is clean

    // Staging: thread t -> row (t>>2) (+128 for 2nd issue), stored chunk t&3.
    // Stored chunk c_st of row R holds global chunk c_st ^ ((R>>1)&3).
    const int srow   = t >> 2;                       // 0..127
    const int schunk = (t & 3) ^ ((t >> 3) & 3);     // pre-swizzled source
    const __hip_bfloat16* aG = vt + (size_t)(m0 + srow) * DV + schunk * 8;
    const __hip_bfloat16* bG = wt + (size_t)(n0 + srow) * DV + schunk * 8;

    // stage item p (0..3) of K-tile k into buf: ks=p>>1, mat=p&1 (0=A,1=B)
    auto STAGE_ITEM = [&](int buf, int k, int p) {
        const int ks = p >> 1, mat = p & 1;
        const __hip_bfloat16* g = (mat ? bG : aG) + (size_t)k * 64 + ks * 32;
        char* dst = lds + buf * 65536 + ks * 32768 + mat * 16384 + t * 16;
        async_copy16(g, dst);
        async_copy16(g + (size_t)128 * DV, dst + 8192);
    };

    // ds_read fragment addressing (bytes)
    const int rchk = ((lane >> 4) ^ (((lane & 15) >> 1) & 3)) * 16;
    const int aRow = (wr * 128 + (lane & 15)) * 64;
    const int bRow = (wc * 64 + (lane & 15)) * 64;

    f32x4 acc[8][4];
#pragma unroll
    for (int i = 0; i < 8; ++i)
#pragma unroll
        for (int j = 0; j < 4; ++j) acc[i][j] = (f32x4){0.f, 0.f, 0.f, 0.f};

    // prologue: tile 0, all 4 items (8 issues); wait ks0 (4 newest remain)
    STAGE_ITEM(0, 0, 0); STAGE_ITEM(0, 0, 1);
    STAGE_ITEM(0, 0, 2); STAGE_ITEM(0, 0, 3);
    asm volatile("s_waitcnt vmcnt(4)" ::: "memory");
    __builtin_amdgcn_s_barrier();

    for (int kt = 0; kt < 32; ++kt) {
        const int cur = kt & 1;
        const char* Xb = lds + cur * 65536;
        bf16x8 bfr[4];
#pragma unroll
        for (int p = 0; p < 4; ++p) {
            const int ks = p >> 1, mh = p & 1;
            const char* Ar = Xb + ks * 32768;
            bf16x8 afr[4];
#pragma unroll
            for (int q = 0; q < 4; ++q)
                afr[q] = *(const bf16x8*)(Ar + aRow + (mh * 64 + q * 16) * 64 + rchk);
            if (mh == 0) {
#pragma unroll
                for (int ni = 0; ni < 4; ++ni)
                    bfr[ni] = *(const bf16x8*)(Ar + 16384 + bRow + (ni * 16) * 64 + rchk);
            }
            if (kt < 31) STAGE_ITEM(cur ^ 1, kt + 1, p);
            if (p == 1) {
                if (kt < 31) asm volatile("s_waitcnt vmcnt(4)" ::: "memory");
                else         asm volatile("s_waitcnt vmcnt(0)" ::: "memory");
            } else if (p == 3 && kt < 31) {
                asm volatile("s_waitcnt vmcnt(4)" ::: "memory");
            }
            __builtin_amdgcn_s_barrier();
            __builtin_amdgcn_s_setprio(1);
#pragma unroll
            for (int q = 0; q < 4; ++q)
#pragma unroll
                for (int ni = 0; ni < 4; ++ni)
                    acc[mh * 4 + q][ni] = __builtin_amdgcn_mfma_f32_16x16x32_bf16(
                        afr[q], bfr[ni], acc[mh * 4 + q][ni], 0, 0, 0);
            __builtin_amdgcn_s_setprio(0);
            __builtin_amdgcn_s_barrier();
        }
    }

    // ---- fused epilogue ----
    __syncthreads();                   // staging LDS is now dead
    float* sc = (float*)lds;           // [4][256][4] per-wc partials

    // C/D layout: col = lane&15 (+16*ni), row = (lane>>4)*4 + rr (+16*mi)
    // acc[mi] rows: (mi>>2)*64 + (mi&3)*16 == mi*16 (identical mapping)
    const int colb_l = wc * 64 + (lane & 15);
    const int colb_g = n0 + colb_l;
    float bvv[4];
    float4 wv[4];
#pragma unroll
    for (int ni = 0; ni < 4; ++ni) {
        bvv[ni] = bvp[colb_g + ni * 16];
        wv[ni]  = *(const float4*)(wa_s + (colb_l + ni * 16) * 4);
    }
#pragma unroll
    for (int mi = 0; mi < 8; ++mi) {
#pragma unroll
        for (int rr = 0; rr < 4; ++rr) {
            int lrow = wr * 128 + mi * 16 + ((lane >> 4) << 2) + rr;  // 0..255
            int row  = m0 + lrow;
            int qoff = (row >= bs1 ? 256 : 0) + (row >= bs2 ? 256 : 0);
            float p0 = 0.f, p1 = 0.f, p2 = 0.f, p3 = 0.f;
#pragma unroll
            for (int ni = 0; ni < 4; ++ni) {
                float xv = fast_tanh(acc[mi][ni][rr] + bvv[ni]);
                float xa = fast_tanh(xv * qs[qoff + colb_l + ni * 16]);
                p0 += xa * wv[ni].x; p1 += xa * wv[ni].y;
                p2 += xa * wv[ni].z; p3 += xa * wv[ni].w;
            }
#pragma unroll
            for (int mk = 1; mk < 16; mk <<= 1) {
                p0 += __shfl_xor(p0, mk); p1 += __shfl_xor(p1, mk);
                p2 += __shfl_xor(p2, mk); p3 += __shfl_xor(p3, mk);
            }
            // each (wc, lrow) written exactly once (wr splits lrow ranges)
            if ((lane & 15) == 0)
                *(float4*)(sc + ((size_t)wc * 256 + lrow) * 4) =
                    (float4){p0, p1, p2, p3};
        }
    }
    __syncthreads();
    if (t < 256) {
        float4 s0 = *(float4*)(sc + (0 * 256 + t) * 4);
        float4 s1 = *(float4*)(sc + (1 * 256 + t) * 4);
        float4 s2 = *(float4*)(sc + (2 * 256 + t) * 4);
        float4 s3 = *(float4*)(sc + (3 * 256 + t) * 4);
        float4 s = {s0.x + s1.x + s2.x + s3.x, s0.y + s1.y + s2.y + s3.y,
                    s0.z + s1.z + s2.z + s3.z, s0.w + s1.w + s2.w + s3.w};
        *(float4*)(scores_p + ((size_t)nt * MROWS + m0 + t) * 4) = s;
    }
}

// ---------------------------------------------------------------------------
// K2: sum score partials -> softmax over s -> glimpse pooling (512-ch chunk).
// ---------------------------------------------------------------------------
__global__ __launch_bounds__(256) void softmax_pool(
    const float* __restrict__ scores_p,
    const __hip_bfloat16* __restrict__ vt,
    float* __restrict__ vatt) {
    __shared__ __align__(16) float att[SS * GG];
    const int b = blockIdx.y;
    const int t = threadIdx.x;
    if (t < SS) {
        float4 s = {0.f, 0.f, 0.f, 0.f};
#pragma unroll
        for (int ntile = 0; ntile < NT; ++ntile) {
            float4 p = *(const float4*)(scores_p + ((size_t)ntile * MROWS + b * SS + t) * 4);
            s.x += p.x; s.y += p.y; s.z += p.z; s.w += p.w;
        }
        *(float4*)(att + t * 4) = s;
    }
    __syncthreads();
    {
        const int g = t >> 6;
        const int lane = t & 63;
        float mx = -3.0e38f;
        for (int s = lane; s < SS; s += 64) mx = fmaxf(mx, att[s * 4 + g]);
#pragma unroll
        for (int m = 32; m > 0; m >>= 1) mx = fmaxf(mx, __shfl_xor(mx, m));
        float sum = 0.f;
        for (int s = lane; s < SS; s += 64) sum += __expf(att[s * 4 + g] - mx);
#pragma unroll
        for (int m = 32; m > 0; m >>= 1) sum += __shfl_xor(sum, m);
        float inv = __builtin_amdgcn_rcpf(sum);
        for (int s = lane; s < SS; s += 64) att[s * 4 + g] = __expf(att[s * 4 + g] - mx) * inv;
    }
    __syncthreads();
    const int c = blockIdx.x * 512 + t * 2;
    const __hip_bfloat16* vp = vt + (size_t)b * SS * DV + c;
    float a00 = 0, a01 = 0, a02 = 0, a03 = 0;
    float a10 = 0, a11 = 0, a12 = 0, a13 = 0;
#pragma unroll 4
    for (int s = 0; s < SS; ++s) {
        unsigned u = *(const unsigned*)(vp + (size_t)s * DV);
        float v0 = __uint_as_float(u << 16);
        float v1 = __uint_as_float(u & 0xffff0000u);
        float4 aw = *(const float4*)(att + s * 4);
        a00 += v0 * aw.x; a01 += v0 * aw.y; a02 += v0 * aw.z; a03 += v0 * aw.w;
        a10 += v1 * aw.x; a11 += v1 * aw.y; a12 += v1 * aw.z; a13 += v1 * aw.w;
    }
    float* vb = vatt + (size_t)b * GG * DV;
    vb[0 * DV + c] = a00; vb[0 * DV + c + 1] = a10;
    vb[1 * DV + c] = a01; vb[1 * DV + c + 1] = a11;
    vb[2 * DV + c] = a02; vb[2 * DV + c + 1] = a12;
    vb[3 * DV + c] = a03; vb[3 * DV + c + 1] = a13;
}

// ---------------------------------------------------------------------------
extern "C" void kernel_launch(void* const* d_in, const int* in_sizes, int n_in,
                              void* d_out, int out_size, void* d_ws, size_t ws_size,
                              hipStream_t stream) {
    const float* input_v = (const float*)d_in[0];
    const float* x_q     = (const float*)d_in[1];
    const float* Wv      = (const float*)d_in[2];
    const float* bv      = (const float*)d_in[3];
    const float* Wq_att  = (const float*)d_in[4];
    const float* bq_att  = (const float*)d_in[5];
    const float* Wa      = (const float*)d_in[6];
    // d_in[7] = ba: constant over softmax axis -> cancels, unused.
    const float* Wf      = (const float*)d_in[8];
    const float* bf_     = (const float*)d_in[9];
    const float* Wqf     = (const float*)d_in[10];
    const float* bqf     = (const float*)d_in[11];
    const float* Wc      = (const float*)d_in[12];
    const float* bc      = (const float*)d_in[13];
    float* out = (float*)d_out;

    char* wsb = (char*)d_ws;
    size_t off = 0;
    auto carve = [&](size_t bytes) -> void* {
        void* p = wsb + off;
        off += (bytes + 255) & ~(size_t)255;
        return p;
    };
    __hip_bfloat16* vt  = (__hip_bfloat16*)carve((size_t)MROWS * DV * 2);   // 102.8 MB
    __hip_bfloat16* wvt = (__hip_bfloat16*)carve((size_t)DAP * DV * 2);     //   5.2 MB
    float* Cp       = (float*)carve((size_t)KSPLIT * 128 * NQ * 4);         //  13.6 MB
    float* scores_p = (float*)carve((size_t)NT * MROWS * GG * 4);           //   2.0 MB
    float* qatt = (float*)carve((size_t)BB * DAP * 4);
    float* qfus = (float*)carve((size_t)BB * DH * 4);
    float* bvp  = (float*)carve((size_t)DAP * 4);
    float* wap  = (float*)carve((size_t)DAP * GG * 4);
    float* vatt = (float*)carve((size_t)BB * GG * DV * 4);
    float* xbuf = (float*)carve((size_t)BB * DH * 4);
    (void)ws_size; (void)n_in; (void)in_sizes; (void)out_size;

    pad_misc<<<dim3(20), 256, 0, stream>>>(bv, Wa, bvp, wap);
    transpose_v<<<dim3(DV / 64, 4, BB), 256, 0, stream>>>(input_v, vt);
    transpose_w<<<dim3(DAP / 64, DV / 64), 256, 0, stream>>>(Wv, wvt);

    // merged q-branch GEMM (split-K fp32): cols [0,1280)=Wq_att, [1280,3328)=Wqf
    gemm_partial<2><<<dim3(NQ / 64, KSPLIT), 256, 0, stream>>>(
        x_q, DQ, Wq_att, Wqf, Cp, NQ);
    epilogue_q<<<dim3(NQ / 256, BB), 256, 0, stream>>>(Cp, bq_att, bqf, qatt, qfus);

    // big MFMA GEMM with fused score reduction -> scores_p (per-ntile partials)
    // grid: 12 groups of (8 mt x 5 nt) + tail 10 = 490 blocks of 512 threads
    big_gemm<<<dim3(490), 512, 0, stream>>>(vt, wvt, bvp, qatt, wap, scores_p);

    // softmax over spatial + glimpse pooling -> vatt [128][4][2048]
    softmax_pool<<<dim3(4, BB), 256, 0, stream>>>(scores_p, vt, vatt);

    // glimpse fusion: xbuf = tanh(tanh(vatt@Wf + bf) * qfus)
    gemm_partial<1><<<dim3(DH / 64, KSPLIT), 256, 0, stream>>>(
        vatt, GG * DV, Wf, nullptr, Cp, DH);
    gemm_epilogue<2><<<dim3(DH / 256, BB), 256, 0, stream>>>(
        Cp, DH, DH, bf_, qfus, xbuf, DH);

    // classifier: out = xbuf @ Wc + bc
    gemm_partial<0><<<dim3(NANSP / 64, KSPLIT), 256, 0, stream>>>(
        xbuf, DH, Wc, nullptr, Cp, NANSP);
    gemm_epilogue<0><<<dim3(NANSP / 256 + 1, BB), 256, 0, stream>>>(
        Cp, NANSP, NANS, bc, nullptr, out, NANS);
}

// Round 3
// 645.957 us; speedup vs baseline: 1.2052x; 1.0491x over previous
//
#include <hip/hip_runtime.h>
#include <hip/hip_bf16.h>

// Problem constants
#define BB   128
#define DV   2048
#define SS   196
#define DQ   2048
#define DA   1200
#define DAP  1280      // DA padded to 5*256 MFMA n-tiles
#define GG   4
#define DH   2048
#define NANS 3000
#define NANSP 3008     // 47*64
#define MROWS (BB*SS)  // 25088 = 196 * 128 exactly
#define NT   5         // n-tiles (256-wide) in big GEMM
#define KSPLIT 8
#define KCHUNK (DV/KSPLIT)  // 256
#define NQ   (DAP + DH)     // 3328 merged q-branch cols

typedef __attribute__((ext_vector_type(8))) short bf16x8;
typedef __attribute__((ext_vector_type(4))) float f32x4;

__device__ __forceinline__ float fast_tanh(float x) {
    float e = __expf(2.0f * x);
    return 1.0f - 2.0f * __builtin_amdgcn_rcpf(e + 1.0f);
}

__device__ __forceinline__ void async_copy16(const void* gsrc, void* ldst) {
    __builtin_amdgcn_global_load_lds(
        (const __attribute__((address_space(1))) void*)gsrc,
        (__attribute__((address_space(3))) void*)ldst, 16, 0, 0);
}

// pad bv (DA->DAP) and Wa ([DA][4] -> [DAP][4], pad rows 0)
__global__ void pad_misc(const float* __restrict__ bv, const float* __restrict__ Wa,
                         float* __restrict__ bvp, float* __restrict__ wap) {
    int i = blockIdx.x * 256 + threadIdx.x;
    if (i < DAP) bvp[i] = (i < DA) ? bv[i] : 0.f;
    if (i < DAP * GG) {
        int d = i >> 2;
        wap[i] = (d < DA) ? Wa[i] : 0.f;
    }
}

// ---------------------------------------------------------------------------
// K0a: v [B][DV][S] fp32 -> v_t [(b*S+s)][DV] bf16.  No LDS.
// Lane map: lane = s_local*4 + cq  (16 s x 4 chunks of 8 ch per wave).
// Loads: per instr, 4 x 64B fully-used segments (16 consecutive s).
// Stores: each 4-lane group (fixed s) writes 64B contiguous -> full lines.
// ---------------------------------------------------------------------------
__global__ __launch_bounds__(256) void transpose_v(const float* __restrict__ v,
                                                   __hip_bfloat16* __restrict__ vt) {
    const int b    = blockIdx.z;
    const int t    = threadIdx.x;
    const int lane = t & 63;
    const int w    = t >> 6;
    const int sl   = lane >> 2;          // 0..15
    const int cq   = lane & 3;           // 0..3
    const int s    = blockIdx.y * 16 + sl;
    const int c0   = blockIdx.x * 128 + w * 32 + cq * 8;
    if (s >= SS) return;
    const float* src = v + (size_t)b * DV * SS + (size_t)c0 * SS + s;
    float f[8];
#pragma unroll
    for (int i = 0; i < 8; ++i) f[i] = src[(size_t)i * SS];
    union { bf16x8 v8; __hip_bfloat16 h[8]; } u;
#pragma unroll
    for (int i = 0; i < 8; ++i) u.h[i] = __float2bfloat16(f[i]);
    *(bf16x8*)(vt + ((size_t)b * SS + s) * DV + c0) = u.v8;
}

// ---------------------------------------------------------------------------
// K0b: Wv [DV][DA] fp32 -> wvt [DAP][DV] bf16 (B^T layout), pad rows zeroed
// ---------------------------------------------------------------------------
__global__ __launch_bounds__(256) void transpose_w(const float* __restrict__ Wv,
                                                   __hip_bfloat16* __restrict__ wvt) {
    __shared__ float tile[64][65];
    const int d0 = blockIdx.x * 64;
    const int c0 = blockIdx.y * 64;
    const int t  = threadIdx.x;
    const int col  = t & 63;
    const int rowb = t >> 6;
#pragma unroll
    for (int i = 0; i < 16; ++i) {
        int c = rowb + i * 4;
        int d = d0 + col;
        tile[c][col] = (d < DA) ? Wv[(size_t)(c0 + c) * DA + d] : 0.f;
    }
    __syncthreads();
#pragma unroll
    for (int i = 0; i < 16; ++i) {
        int dl = rowb + i * 4;
        wvt[(size_t)(d0 + dl) * DV + c0 + col] = __float2bfloat16(tile[col][dl]);
    }
}

// ---------------------------------------------------------------------------
// Split-K fp32 partial GEMM: Cp[ks][128][Npad] = A[128,kchunk] * B[kchunk,64tile]
// grid (ntiles, KSPLIT). SEL 0: classifier | SEL 1: glimpse fusion | SEL 2:
// merged q-branch (cols [0,DAP) -> Wq_att, cols [DAP,NQ) -> Wqf).
// ---------------------------------------------------------------------------
template <int SEL>
__global__ __launch_bounds__(256) void gemm_partial(
    const float* __restrict__ A, int lda,
    const float* __restrict__ Bm, const float* __restrict__ B2,
    float* __restrict__ Cp, int Npad) {
    __shared__ float As[64 * 132];   // As[kk][m]
    __shared__ float Bs[64 * 68];    // Bs[kk][n]
    const int t     = threadIdx.x;
    const int n0    = blockIdx.x * 64;
    const int kbase = blockIdx.y * KCHUNK;

    const float* Aeff = A;
    const float* Beff;
    int ldb, ncol0, nlim;
    if (SEL == 0) {            // classifier: B=Wc [2048][3000]
        Beff = Bm; ldb = NANS; ncol0 = n0; nlim = NANS;
    } else if (SEL == 1) {     // fusion: A=vatt per glimpse, B=Wf[g] [2048][512]
        int gg = n0 >> 9;
        Aeff = A + gg * 2048;
        Beff = Bm + (size_t)gg * 2048 * 512;
        ldb = 512; ncol0 = n0 & 511; nlim = 1 << 30;
    } else {                   // merged q-branch
        if (n0 < DAP) { Beff = Bm; ldb = DA; ncol0 = n0;      nlim = DA; }
        else          { Beff = B2; ldb = DH; ncol0 = n0 - DAP; nlim = 1 << 30; }
    }

    const int tm = (t & 31) * 4;
    const int tn = (t >> 5) * 8;
    float acc[4][8] = {};

    for (int k0 = kbase; k0 < kbase + KCHUNK; k0 += 64) {
        {
            int kk = t & 63, mb = (t >> 6) * 32;
#pragma unroll
            for (int i = 0; i < 32; ++i)
                As[kk * 132 + mb + i] = Aeff[(size_t)(mb + i) * lda + k0 + kk];
        }
        {
            int j = t & 63, kr = t >> 6;
            bool ok = (ncol0 + j) < nlim;
#pragma unroll
            for (int i = 0; i < 16; ++i) {
                int k = kr + i * 4;
                Bs[k * 68 + j] = ok ? Beff[(size_t)(k0 + k) * ldb + ncol0 + j] : 0.f;
            }
        }
        __syncthreads();
#pragma unroll
        for (int kk = 0; kk < 64; ++kk) {
            const float4 av = *(const float4*)(As + kk * 132 + tm);
            const float4 b0 = *(const float4*)(Bs + kk * 68 + tn);
            const float4 b1 = *(const float4*)(Bs + kk * 68 + tn + 4);
            const float am[4] = {av.x, av.y, av.z, av.w};
#pragma unroll
            for (int i = 0; i < 4; ++i) {
                acc[i][0] += am[i] * b0.x; acc[i][1] += am[i] * b0.y;
                acc[i][2] += am[i] * b0.z; acc[i][3] += am[i] * b0.w;
                acc[i][4] += am[i] * b1.x; acc[i][5] += am[i] * b1.y;
                acc[i][6] += am[i] * b1.z; acc[i][7] += am[i] * b1.w;
            }
        }
        __syncthreads();
    }
#pragma unroll
    for (int i = 0; i < 4; ++i) {
        size_t base = ((size_t)blockIdx.y * 128 + tm + i) * Npad + n0 + tn;
        float4 v0 = {acc[i][0], acc[i][1], acc[i][2], acc[i][3]};
        float4 v1 = {acc[i][4], acc[i][5], acc[i][6], acc[i][7]};
        *(float4*)(Cp + base) = v0;
        *(float4*)(Cp + base + 4) = v1;
    }
}

// Generic epilogue: MODE 0: +bias (classifier) | MODE 2: MLB glimpse fusion
template <int MODE>
__global__ __launch_bounds__(256) void gemm_epilogue(
    const float* __restrict__ Cp, int Npad, int Nreal,
    const float* __restrict__ bias, const float* __restrict__ aux,
    float* __restrict__ out, int ldo) {
    int n = blockIdx.x * 256 + threadIdx.x;
    int m = blockIdx.y;
    if (n >= Npad) return;
    float s = 0.f;
#pragma unroll
    for (int ks = 0; ks < KSPLIT; ++ks)
        s += Cp[((size_t)ks * 128 + m) * Npad + n];
    if (MODE == 0) {
        if (n >= Nreal) return;
        out[(size_t)m * ldo + n] = s + bias[n];
    } else {
        float xv = fast_tanh(s + bias[n]);
        out[(size_t)m * ldo + n] = fast_tanh(xv * aux[(size_t)m * 2048 + n]);
    }
}

// q-branch epilogue: cols [0,DAP) -> qatt (tanh, pad->0), [DAP,NQ) -> qfus
__global__ __launch_bounds__(256) void epilogue_q(
    const float* __restrict__ Cp,
    const float* __restrict__ bqa, const float* __restrict__ bqf,
    float* __restrict__ qatt, float* __restrict__ qfus) {
    int n = blockIdx.x * 256 + threadIdx.x;
    int m = blockIdx.y;
    if (n >= NQ) return;
    float s = 0.f;
#pragma unroll
    for (int ks = 0; ks < KSPLIT; ++ks)
        s += Cp[((size_t)ks * 128 + m) * NQ + n];
    if (n < DAP) {
        qatt[(size_t)m * DAP + n] = (n < DA) ? fast_tanh(s + bqa[n]) : 0.f;
    } else {
        int j = n - DAP;
        qfus[(size_t)m * DH + j] = fast_tanh(s + bqf[j]);
    }
}

// ---------------------------------------------------------------------------
// K1: big MFMA GEMM, 256x256 tile, BK=64, 8 waves (2M x 4N), 4-phase
// schedule per K-tile (T3+T4), SINGLE barrier per phase (pre-MFMA).
// Safety ledger for single-barrier: all buf[cur] ds_reads occur at phase
// tops BEFORE that phase's barrier; stages only target buf[cur^1] regions
// whose last ds_read completed >=2 barriers earlier (in-order lgkm FIFO:
// a wave past barrier B has completed all ds_reads issued >=2 phases
// before B). Each vmcnt wait precedes a barrier that precedes the
// dependent read, so other waves' landings are made visible. vmcnt(4) at
// p1/p3 keeps 4 issues in flight across barriers (drains only at kt=31).
// Swizzle within 64B rows: stored chunk = g ^ ((row>>1)&3) -> 2-way (free)
// b128 reads; gload_lds dest wave-linear (t*16), source pre-swizzled.
// Fused epilogue: per-wc score partials -> scores_p (no atomics).
// ---------------------------------------------------------------------------
__global__ __launch_bounds__(512, 2) void big_gemm(
    const __hip_bfloat16* __restrict__ vt,
    const __hip_bfloat16* __restrict__ wt,
    const float* __restrict__ bvp,
    const float* __restrict__ qatt,
    const float* __restrict__ wap,
    float* __restrict__ scores_p) {
    // lds: buf*65536 + ks*32768 + mat*16384 + row*64 + chunk*16  (bytes)
    __shared__ __align__(16) char lds[131072];
    __shared__ __align__(16) float wa_s[256 * 4];
    __shared__ float qs[3 * 256];

    const int t    = threadIdx.x;
    const int lane = t & 63;
    const int w    = t >> 6;        // wave 0..7
    const int wr   = w >> 2;        // m-half 0..1
    const int wc   = w & 3;         // n-quarter 0..3

    // grid de-swizzle: 12 groups of (8 mt x 5 nt) + tail (2 mt x 5 nt)
    int bid = blockIdx.x;
    int grp = bid / 40, r = bid % 40;
    int mt, nt;
    if (grp < 12) { mt = grp * 8 + (r & 7); nt = r >> 3; }
    else          { mt = 96 + (r & 1);      nt = r >> 1; }
    const int m0 = mt * 256, n0 = nt * 256;
    const int b_lo = m0 / SS;              // 256-row tile spans <= 3 batches
    const int bs1  = (b_lo + 1) * SS;
    const int bs2  = (b_lo + 2) * SS;

    // small prologue loads (wa tile, q rows for up to 3 batches)
    if (t < 256) *(float4*)(wa_s + t * 4) = *(const float4*)(wap + (n0 + t) * 4);
    {
        int j = t >> 8, c = t & 255;       // j=0,1 over 512 threads
        int b = b_lo + j;
        qs[t] = (b < BB) ? qatt[(size_t)b * DAP + n0 + c] : 0.f;
        if (t < 256) {
            int b2 = b_lo + 2;
            qs[512 + t] = (b2 < BB) ? qatt[(size_t)b2 * DAP + n0 + t] : 0.f;
        }
    }
    __syncthreads();   // drain prologue vmem so the counted vmcnt is clean

    // Staging: thread t -> row (t>>2) (+128 for 2nd issue), stored chunk t&3.
    // Stored chunk c_st of row R holds global chunk c_st ^ ((R>>1)&3).
    const int srow   = t >> 2;                       // 0..127
    const int schunk = (t & 3) ^ ((t >> 3) & 3);     // pre-swizzled source
    const __hip_bfloat16* aG = vt + (size_t)(m0 + srow) * DV + schunk * 8;
    const __hip_bfloat16* bG = wt + (size_t)(n0 + srow) * DV + schunk * 8;

    // stage item p (0..3) of K-tile k into buf: ks=p>>1, mat=p&1 (0=A,1=B)
    auto STAGE_ITEM = [&](int buf, int k, int p) {
        const int ks = p >> 1, mat = p & 1;
        const __hip_bfloat16* g = (mat ? bG : aG) + (size_t)k * 64 + ks * 32;
        char* dst = lds + buf * 65536 + ks * 32768 + mat * 16384 + t * 16;
        async_copy16(g, dst);
        async_copy16(g + (size_t)128 * DV, dst + 8192);
    };

    // ds_read fragment addressing (bytes)
    const int rchk = ((lane >> 4) ^ (((lane & 15) >> 1) & 3)) * 16;
    const int aRow = (wr * 128 + (lane & 15)) * 64;
    const int bRow = (wc * 64 + (lane & 15)) * 64;

    f32x4 acc[8][4];
#pragma unroll
    for (int i = 0; i < 8; ++i)
#pragma unroll
        for (int j = 0; j < 4; ++j) acc[i][j] = (f32x4){0.f, 0.f, 0.f, 0.f};

    // prologue: tile 0, all 4 items (8 issues); wait ks0 (4 newest remain)
    STAGE_ITEM(0, 0, 0); STAGE_ITEM(0, 0, 1);
    STAGE_ITEM(0, 0, 2); STAGE_ITEM(0, 0, 3);
    asm volatile("s_waitcnt vmcnt(4)" ::: "memory");
    __builtin_amdgcn_s_barrier();

    for (int kt = 0; kt < 32; ++kt) {
        const int cur = kt & 1;
        const char* Xb = lds + cur * 65536;
        bf16x8 bfr[4];
#pragma unroll
        for (int p = 0; p < 4; ++p) {
            const int ks = p >> 1, mh = p & 1;
            const char* Ar = Xb + ks * 32768;
            bf16x8 afr[4];
#pragma unroll
            for (int q = 0; q < 4; ++q)
                afr[q] = *(const bf16x8*)(Ar + aRow + (mh * 64 + q * 16) * 64 + rchk);
            if (mh == 0) {
#pragma unroll
                for (int ni = 0; ni < 4; ++ni)
                    bfr[ni] = *(const bf16x8*)(Ar + 16384 + bRow + (ni * 16) * 64 + rchk);
            }
            if (kt < 31) STAGE_ITEM(cur ^ 1, kt + 1, p);
            if (p == 1) {
                if (kt < 31) asm volatile("s_waitcnt vmcnt(4)" ::: "memory");
                else         asm volatile("s_waitcnt vmcnt(0)" ::: "memory");
            } else if (p == 3 && kt < 31) {
                asm volatile("s_waitcnt vmcnt(4)" ::: "memory");
            }
            __builtin_amdgcn_s_barrier();
            __builtin_amdgcn_s_setprio(1);
#pragma unroll
            for (int q = 0; q < 4; ++q)
#pragma unroll
                for (int ni = 0; ni < 4; ++ni)
                    acc[mh * 4 + q][ni] = __builtin_amdgcn_mfma_f32_16x16x32_bf16(
                        afr[q], bfr[ni], acc[mh * 4 + q][ni], 0, 0, 0);
            __builtin_amdgcn_s_setprio(0);
            // no post-MFMA barrier: waves may drift one phase; all LDS
            // hazards covered by the pre-MFMA barrier chain (see ledger).
        }
    }

    // ---- fused epilogue ----
    __syncthreads();                   // staging LDS is now dead
    float* sc = (float*)lds;           // [4][256][4] per-wc partials

    // C/D layout: col = lane&15 (+16*ni), row = (lane>>4)*4 + rr (+16*mi)
    const int colb_l = wc * 64 + (lane & 15);
    const int colb_g = n0 + colb_l;
    float bvv[4];
    float4 wv[4];
#pragma unroll
    for (int ni = 0; ni < 4; ++ni) {
        bvv[ni] = bvp[colb_g + ni * 16];
        wv[ni]  = *(const float4*)(wa_s + (colb_l + ni * 16) * 4);
    }
#pragma unroll
    for (int mi = 0; mi < 8; ++mi) {
#pragma unroll
        for (int rr = 0; rr < 4; ++rr) {
            int lrow = wr * 128 + mi * 16 + ((lane >> 4) << 2) + rr;  // 0..255
            int row  = m0 + lrow;
            int qoff = (row >= bs1 ? 256 : 0) + (row >= bs2 ? 256 : 0);
            float p0 = 0.f, p1 = 0.f, p2 = 0.f, p3 = 0.f;
#pragma unroll
            for (int ni = 0; ni < 4; ++ni) {
                float xv = fast_tanh(acc[mi][ni][rr] + bvv[ni]);
                float xa = fast_tanh(xv * qs[qoff + colb_l + ni * 16]);
                p0 += xa * wv[ni].x; p1 += xa * wv[ni].y;
                p2 += xa * wv[ni].z; p3 += xa * wv[ni].w;
            }
#pragma unroll
            for (int mk = 1; mk < 16; mk <<= 1) {
                p0 += __shfl_xor(p0, mk); p1 += __shfl_xor(p1, mk);
                p2 += __shfl_xor(p2, mk); p3 += __shfl_xor(p3, mk);
            }
            // each (wc, lrow) written exactly once (wr splits lrow ranges)
            if ((lane & 15) == 0)
                *(float4*)(sc + ((size_t)wc * 256 + lrow) * 4) =
                    (float4){p0, p1, p2, p3};
        }
    }
    __syncthreads();
    if (t < 256) {
        float4 s0 = *(float4*)(sc + (0 * 256 + t) * 4);
        float4 s1 = *(float4*)(sc + (1 * 256 + t) * 4);
        float4 s2 = *(float4*)(sc + (2 * 256 + t) * 4);
        float4 s3 = *(float4*)(sc + (3 * 256 + t) * 4);
        float4 s = {s0.x + s1.x + s2.x + s3.x, s0.y + s1.y + s2.y + s3.y,
                    s0.z + s1.z + s2.z + s3.z, s0.w + s1.w + s2.w + s3.w};
        *(float4*)(scores_p + ((size_t)nt * MROWS + m0 + t) * 4) = s;
    }
}

// ---------------------------------------------------------------------------
// K2: sum score partials -> softmax over s -> glimpse pooling (512-ch chunk).
// ---------------------------------------------------------------------------
__global__ __launch_bounds__(256) void softmax_pool(
    const float* __restrict__ scores_p,
    const __hip_bfloat16* __restrict__ vt,
    float* __restrict__ vatt) {
    __shared__ __align__(16) float att[SS * GG];
    const int b = blockIdx.y;
    const int t = threadIdx.x;
    if (t < SS) {
        float4 s = {0.f, 0.f, 0.f, 0.f};
#pragma unroll
        for (int ntile = 0; ntile < NT; ++ntile) {
            float4 p = *(const float4*)(scores_p + ((size_t)ntile * MROWS + b * SS + t) * 4);
            s.x += p.x; s.y += p.y; s.z += p.z; s.w += p.w;
        }
        *(float4*)(att + t * 4) = s;
    }
    __syncthreads();
    {
        const int g = t >> 6;
        const int lane = t & 63;
        float mx = -3.0e38f;
        for (int s = lane; s < SS; s += 64) mx = fmaxf(mx, att[s * 4 + g]);
#pragma unroll
        for (int m = 32; m > 0; m >>= 1) mx = fmaxf(mx, __shfl_xor(mx, m));
        float sum = 0.f;
        for (int s = lane; s < SS; s += 64) sum += __expf(att[s * 4 + g] - mx);
#pragma unroll
        for (int m = 32; m > 0; m >>= 1) sum += __shfl_xor(sum, m);
        float inv = __builtin_amdgcn_rcpf(sum);
        for (int s = lane; s < SS; s += 64) att[s * 4 + g] = __expf(att[s * 4 + g] - mx) * inv;
    }
    __syncthreads();
    const int c = blockIdx.x * 512 + t * 2;
    const __hip_bfloat16* vp = vt + (size_t)b * SS * DV + c;
    float a00 = 0, a01 = 0, a02 = 0, a03 = 0;
    float a10 = 0, a11 = 0, a12 = 0, a13 = 0;
#pragma unroll 4
    for (int s = 0; s < SS; ++s) {
        unsigned u = *(const unsigned*)(vp + (size_t)s * DV);
        float v0 = __uint_as_float(u << 16);
        float v1 = __uint_as_float(u & 0xffff0000u);
        float4 aw = *(const float4*)(att + s * 4);
        a00 += v0 * aw.x; a01 += v0 * aw.y; a02 += v0 * aw.z; a03 += v0 * aw.w;
        a10 += v1 * aw.x; a11 += v1 * aw.y; a12 += v1 * aw.z; a13 += v1 * aw.w;
    }
    float* vb = vatt + (size_t)b * GG * DV;
    vb[0 * DV + c] = a00; vb[0 * DV + c + 1] = a10;
    vb[1 * DV + c] = a01; vb[1 * DV + c + 1] = a11;
    vb[2 * DV + c] = a02; vb[2 * DV + c + 1] = a12;
    vb[3 * DV + c] = a03; vb[3 * DV + c + 1] = a13;
}

// ---------------------------------------------------------------------------
extern "C" void kernel_launch(void* const* d_in, const int* in_sizes, int n_in,
                              void* d_out, int out_size, void* d_ws, size_t ws_size,
                              hipStream_t stream) {
    const float* input_v = (const float*)d_in[0];
    const float* x_q     = (const float*)d_in[1];
    const float* Wv      = (const float*)d_in[2];
    const float* bv      = (const float*)d_in[3];
    const float* Wq_att  = (const float*)d_in[4];
    const float* bq_att  = (const float*)d_in[5];
    const float* Wa      = (const float*)d_in[6];
    // d_in[7] = ba: constant over softmax axis -> cancels, unused.
    const float* Wf      = (const float*)d_in[8];
    const float* bf_     = (const float*)d_in[9];
    const float* Wqf     = (const float*)d_in[10];
    const float* bqf     = (const float*)d_in[11];
    const float* Wc      = (const float*)d_in[12];
    const float* bc      = (const float*)d_in[13];
    float* out = (float*)d_out;

    char* wsb = (char*)d_ws;
    size_t off = 0;
    auto carve = [&](size_t bytes) -> void* {
        void* p = wsb + off;
        off += (bytes + 255) & ~(size_t)255;
        return p;
    };
    __hip_bfloat16* vt  = (__hip_bfloat16*)carve((size_t)MROWS * DV * 2);   // 102.8 MB
    __hip_bfloat16* wvt = (__hip_bfloat16*)carve((size_t)DAP * DV * 2);     //   5.2 MB
    float* Cp       = (float*)carve((size_t)KSPLIT * 128 * NQ * 4);         //  13.6 MB
    float* scores_p = (float*)carve((size_t)NT * MROWS * GG * 4);           //   2.0 MB
    float* qatt = (float*)carve((size_t)BB * DAP * 4);
    float* qfus = (float*)carve((size_t)BB * DH * 4);
    float* bvp  = (float*)carve((size_t)DAP * 4);
    float* wap  = (float*)carve((size_t)DAP * GG * 4);
    float* vatt = (float*)carve((size_t)BB * GG * DV * 4);
    float* xbuf = (float*)carve((size_t)BB * DH * 4);
    (void)ws_size; (void)n_in; (void)in_sizes; (void)out_size;

    pad_misc<<<dim3(20), 256, 0, stream>>>(bv, Wa, bvp, wap);
    transpose_v<<<dim3(DV / 128, 13, BB), 256, 0, stream>>>(input_v, vt);
    transpose_w<<<dim3(DAP / 64, DV / 64), 256, 0, stream>>>(Wv, wvt);

    // merged q-branch GEMM (split-K fp32): cols [0,1280)=Wq_att, [1280,3328)=Wqf
    gemm_partial<2><<<dim3(NQ / 64, KSPLIT), 256, 0, stream>>>(
        x_q, DQ, Wq_att, Wqf, Cp, NQ);
    epilogue_q<<<dim3(NQ / 256, BB), 256, 0, stream>>>(Cp, bq_att, bqf, qatt, qfus);

    // big MFMA GEMM with fused score reduction -> scores_p (per-ntile partials)
    // grid: 12 groups of (8 mt x 5 nt) + tail 10 = 490 blocks of 512 threads
    big_gemm<<<dim3(490), 512, 0, stream>>>(vt, wvt, bvp, qatt, wap, scores_p);

    // softmax over spatial + glimpse pooling -> vatt [128][4][2048]
    softmax_pool<<<dim3(4, BB), 256, 0, stream>>>(scores_p, vt, vatt);

    // glimpse fusion: xbuf = tanh(tanh(vatt@Wf + bf) * qfus)
    gemm_partial<1><<<dim3(DH / 64, KSPLIT), 256, 0, stream>>>(
        vatt, GG * DV, Wf, nullptr, Cp, DH);
    gemm_epilogue<2><<<dim3(DH / 256, BB), 256, 0, stream>>>(
        Cp, DH, DH, bf_, qfus, xbuf, DH);

    // classifier: out = xbuf @ Wc + bc
    gemm_partial<0><<<dim3(NANSP / 64, KSPLIT), 256, 0, stream>>>(
        xbuf, DH, Wc, nullptr, Cp, NANSP);
    gemm_epilogue<0><<<dim3(NANSP / 256 + 1, BB), 256, 0, stream>>>(
        Cp, NANSP, NANS, bc, nullptr, out, NANS);
}